// Round 5
// baseline (1273.058 us; speedup 1.0000x reference)
//
#include <hip/hip_runtime.h>
#include <math.h>

#define TOK 8192   // B*S tokens
#define HD  512    // hidden
#define NE  8      // experts
#define DFF 2048   // ffn dim

// ---------- bf16 helpers ----------
typedef __attribute__((ext_vector_type(8))) short bf16x8;
typedef __attribute__((ext_vector_type(4))) float floatx4;

__device__ inline unsigned short f2bf(float f) {
    union { float f; unsigned u; } v; v.f = f;
    unsigned r = v.u + 0x7FFFu + ((v.u >> 16) & 1u);   // round-nearest-even
    return (unsigned short)(r >> 16);
}

// ---------------- gating (fp32, exact) + fused x->bf16 conversion ----------------
__global__ __launch_bounds__(256) void gate_kernel(
    const float* __restrict__ x, const float* __restrict__ gW, const float* __restrict__ gb,
    int* __restrict__ seg_count, float* __restrict__ probs_sum,
    int* __restrict__ seg_token, float* __restrict__ seg_w,
    unsigned short* __restrict__ xb)
{
    __shared__ float sW[HD * NE];
    __shared__ float psum[NE];
    __shared__ int   lcount[NE];
    __shared__ int   lbase[NE];

    int tid = threadIdx.x;
    for (int i = tid; i < HD * NE; i += 256) sW[i] = gW[i];
    if (tid < NE) { psum[tid] = 0.f; lcount[tid] = 0; }
    __syncthreads();

    int t = blockIdx.x * 256 + tid;
    float logit[NE];
    #pragma unroll
    for (int e = 0; e < NE; e++) logit[e] = gb[e];

    const float4* xr4 = reinterpret_cast<const float4*>(x + (size_t)t * HD);
    ushort4* xbw = reinterpret_cast<ushort4*>(xb + (size_t)t * HD);
    for (int j4 = 0; j4 < HD / 4; j4++) {
        float4 xv = xr4[j4];
        int j = j4 * 4;
        ushort4 o; o.x = f2bf(xv.x); o.y = f2bf(xv.y); o.z = f2bf(xv.z); o.w = f2bf(xv.w);
        xbw[j4] = o;
        #pragma unroll
        for (int e = 0; e < NE; e++) {
            logit[e] += xv.x * sW[(j + 0) * NE + e] + xv.y * sW[(j + 1) * NE + e]
                      + xv.z * sW[(j + 2) * NE + e] + xv.w * sW[(j + 3) * NE + e];
        }
    }

    float mx = logit[0];
    #pragma unroll
    for (int e = 1; e < NE; e++) mx = fmaxf(mx, logit[e]);
    float pe[NE]; float s = 0.f;
    #pragma unroll
    for (int e = 0; e < NE; e++) { pe[e] = expf(logit[e] - mx); s += pe[e]; }
    float inv = 1.f / s;
    int l = tid & 63;
    #pragma unroll
    for (int e = 0; e < NE; e++) {          // wave-shuffle reduce, 1 LDS atomic per wave per e
        float v = pe[e] * inv;
        for (int off = 32; off; off >>= 1) v += __shfl_down(v, off);
        if (l == 0) atomicAdd(&psum[e], v);
    }

    // top-2, lowest-index tie break (matches jax.lax.top_k)
    int i0 = 0; float v0 = logit[0];
    #pragma unroll
    for (int e = 1; e < NE; e++) if (logit[e] > v0) { v0 = logit[e]; i0 = e; }
    int i1 = -1; float v1 = -3.4e38f;
    #pragma unroll
    for (int e = 0; e < NE; e++) if (e != i0 && logit[e] > v1) { v1 = logit[e]; i1 = e; }
    float e1 = expf(v1 - v0);
    float w0 = 1.f / (1.f + e1);
    float w1 = e1 / (1.f + e1);

    int r0 = atomicAdd(&lcount[i0], 1);
    int r1 = atomicAdd(&lcount[i1], 1);
    __syncthreads();
    if (tid < NE) lbase[tid] = atomicAdd(&seg_count[tid], lcount[tid]);
    __syncthreads();
    int p0 = lbase[i0] + r0;
    seg_token[i0 * TOK + p0] = t; seg_w[i0 * TOK + p0] = w0;
    int p1 = lbase[i1] + r1;
    seg_token[i1 * TOK + p1] = t; seg_w[i1 * TOK + p1] = w1;

    __syncthreads();
    if (tid < NE) atomicAdd(&probs_sum[tid], psum[tid]);
}

// ---------------- l_aux + counts ----------------
__global__ void finalize_kernel(const int* __restrict__ seg_count,
                                const float* __restrict__ probs_sum,
                                float* __restrict__ out_tail)
{
    int tid = threadIdx.x;
    __shared__ float p2[NE];
    if (tid < NE) {
        float p = probs_sum[tid] * (1.f / (float)TOK);
        p2[tid] = p * p;
        out_tail[1 + tid] = (float)seg_count[tid];
    }
    __syncthreads();
    if (tid == 0) {
        float ssum = 0.f;
        #pragma unroll
        for (int e = 0; e < NE; e++) ssum += p2[e];
        out_tail[0] = ssum * (float)NE;
    }
}

// ---------------- weight transpose: [E][R][C] fp32 -> [E][C][R] bf16 ----------------
__global__ __launch_bounds__(256) void transpose_bf16_kernel(const float* __restrict__ in,
                                                             unsigned short* __restrict__ out,
                                                             int R, int C)
{
    __shared__ float tile[64][65];
    int e = blockIdx.z;
    const float* src = in + (size_t)e * R * C;
    unsigned short* dst = out + (size_t)e * R * C;
    int c0 = blockIdx.x * 64, r0 = blockIdx.y * 64;
    int lc = threadIdx.x & 63, lrw = threadIdx.x >> 6;   // 4 row-groups
    #pragma unroll
    for (int rr = lrw; rr < 64; rr += 4)
        tile[rr][lc] = src[(size_t)(r0 + rr) * C + c0 + lc];
    __syncthreads();
    #pragma unroll
    for (int cc = lrw; cc < 64; cc += 4)
        dst[(size_t)(c0 + cc) * R + r0 + lc] = f2bf(tile[lc][cc]);
}

// ---------------- fused MFMA expert FFN ----------------
// Flat 1-D grid; e = bid & 7 so (with round-robin block->XCD dispatch) each XCD
// mostly runs ONE expert -> its 4 MB bf16 weights fit that XCD's 4 MB L2.
// Block = 64 tokens x one expert x one DFF z-slice. 4 waves.
// (256,2): 2 blocks/CU; acc fits 256-reg budget with NO spill (R2-proven).
#define BMT 64     // tokens per block
#define FK  64     // dff chunk
#define ZN  2      // DFF split factor
#define ZSLICE (DFF / ZN)
#define XS_LD 520  // xs leading dim (bf16): 1040 B -> 2-way bank alias (free)
#define HS_LD 72   // hs leading dim: 144 B -> 2-way bank alias (free)

__global__ __launch_bounds__(256, 2) void ffn_mfma_kernel(
    const unsigned short* __restrict__ xb,
    const unsigned short* __restrict__ W1t,   // [E][DFF][HD] bf16 (n-major)
    const float* __restrict__ b1,
    const unsigned short* __restrict__ W2t,   // [E][HD][DFF] bf16 (n-major)
    const float* __restrict__ b2,
    const int* __restrict__ seg_count, const int* __restrict__ seg_token,
    const float* __restrict__ seg_w, float* __restrict__ out)
{
    int bid = blockIdx.x;
    int e = bid & 7;            // XCD-affinity: same expert -> same XCD (heuristic)
    int rest = bid >> 3;
    int z = rest & (ZN - 1);
    int g = rest >> 1;
    int cnt = seg_count[e];
    int n0 = g * BMT;
    if (n0 >= cnt) return;
    int rows = min(BMT, cnt - n0);

    __shared__ unsigned short xs[BMT * XS_LD];   // 66560 B
    __shared__ unsigned short hs[BMT * HS_LD];   //  9216 B
    __shared__ int   tok_s[BMT];
    __shared__ float wgt_s[BMT];

    int tid = threadIdx.x;
    if (tid < BMT) {
        int idx = (tid < rows) ? (n0 + tid) : n0;            // pad rows duplicate row 0
        tok_s[tid] = seg_token[e * TOK + idx];
        wgt_s[tid] = (tid < rows) ? seg_w[e * TOK + idx] : 0.f;
    }
    __syncthreads();

    // stage x rows (bf16): 4 threads per row, 16B vectors
    {
        int r = tid >> 2, q = tid & 3;
        const uint4* src = (const uint4*)(xb + (size_t)tok_s[r] * HD) + q * 16;
        uint4* dst = (uint4*)&xs[(size_t)r * XS_LD + q * 128];
        #pragma unroll
        for (int i = 0; i < 16; i++) dst[i] = src[i];
    }
    __syncthreads();

    int w  = tid >> 6;          // wave id 0..3
    int l  = tid & 63;
    int lr = l & 15;
    int lk = (l >> 4) * 8;
    int crow = (l >> 4) * 4;
    int mh = w & 1;             // GEMM1 M-half (rows 32*mh .. +32)
    int nh = w >> 1;            // GEMM1 N-half (cols 32*nh .. +32)

    const unsigned short* w1e = W1t + ((size_t)e * DFF + (size_t)z * ZSLICE) * HD;
    const unsigned short* w2e = W2t + (size_t)e * HD * DFF + (size_t)z * ZSLICE;

    floatx4 acc2[4][8];         // 64 M x 128 N per wave
    #pragma unroll
    for (int i = 0; i < 4; i++)
        #pragma unroll
        for (int j = 0; j < 8; j++)
            acc2[i][j] = (floatx4){0.f, 0.f, 0.f, 0.f};

    for (int fc = 0; fc < ZSLICE; fc += FK) {
        // ---- GEMM1: h-chunk(64x64) = xs(64x512) @ W1slice[:, fc:fc+64]
        // wave(mh,nh): M rows 32mh..32mh+32, N cols 32nh..32nh+32 (W1 redundancy 2x)
        floatx4 acc1[2][2];
        #pragma unroll
        for (int i = 0; i < 2; i++)
            #pragma unroll
            for (int t = 0; t < 2; t++)
                acc1[i][t] = (floatx4){0.f, 0.f, 0.f, 0.f};

        const unsigned short* w1c = w1e + ((size_t)fc + 32 * nh) * HD;
        #pragma unroll 4
        for (int ks = 0; ks < HD; ks += 32) {
            bf16x8 a0 = *(const bf16x8*)&xs[(32 * mh + lr) * XS_LD + ks + lk];
            bf16x8 a1 = *(const bf16x8*)&xs[(32 * mh + 16 + lr) * XS_LD + ks + lk];
            bf16x8 b0 = *(const bf16x8*)(w1c + (size_t)lr * HD + ks + lk);
            bf16x8 b1f = *(const bf16x8*)(w1c + (size_t)(16 + lr) * HD + ks + lk);
            acc1[0][0] = __builtin_amdgcn_mfma_f32_16x16x32_bf16(a0, b0, acc1[0][0], 0, 0, 0);
            acc1[0][1] = __builtin_amdgcn_mfma_f32_16x16x32_bf16(a0, b1f, acc1[0][1], 0, 0, 0);
            acc1[1][0] = __builtin_amdgcn_mfma_f32_16x16x32_bf16(a1, b0, acc1[1][0], 0, 0, 0);
            acc1[1][1] = __builtin_amdgcn_mfma_f32_16x16x32_bf16(a1, b1f, acc1[1][1], 0, 0, 0);
        }

        __syncthreads();   // previous GEMM2 done reading hs
        #pragma unroll
        for (int i = 0; i < 2; i++) {
            #pragma unroll
            for (int t = 0; t < 2; t++) {
                float b1v = b1[e * DFF + z * ZSLICE + fc + 32 * nh + 16 * t + lr];
                #pragma unroll
                for (int r = 0; r < 4; r++) {
                    float v = acc1[i][t][r] + b1v;
                    float g = 0.5f * v * (1.f + erff(v * 0.70710678118654752f));  // exact gelu
                    hs[(32 * mh + 16 * i + crow + r) * HS_LD + 32 * nh + 16 * t + lr] = f2bf(g);
                }
            }
        }
        __syncthreads();   // hs ready

        // ---- GEMM2: out(64x512) += h-chunk(64x64) @ W2slice[fc:fc+64, :]
        // wave w: N cols 128w..128w+128 (no redundancy)
        const unsigned short* w2c = w2e + fc;
        #pragma unroll
        for (int ks = 0; ks < FK; ks += 32) {
            bf16x8 af[4];
            #pragma unroll
            for (int i = 0; i < 4; i++)
                af[i] = *(const bf16x8*)&hs[(16 * i + lr) * HS_LD + ks + lk];
            #pragma unroll 4
            for (int j = 0; j < 8; j++) {
                bf16x8 b = *(const bf16x8*)(w2c + (size_t)(128 * w + 16 * j + lr) * DFF + ks + lk);
                #pragma unroll
                for (int i = 0; i < 4; i++)
                    acc2[i][j] = __builtin_amdgcn_mfma_f32_16x16x32_bf16(af[i], b, acc2[i][j], 0, 0, 0);
            }
        }
    }

    // ---- epilogue: (+b2 once, by z==0), scale by gate weight, atomic add
    #pragma unroll
    for (int j = 0; j < 8; j++) {
        int n = 128 * w + 16 * j + lr;
        float b2v = (z == 0) ? b2[e * HD + n] : 0.f;
        #pragma unroll
        for (int i = 0; i < 4; i++) {
            #pragma unroll
            for (int r = 0; r < 4; r++) {
                int m = 16 * i + crow + r;
                float val = (acc2[i][j][r] + b2v) * wgt_s[m];
                atomicAdd(&out[(size_t)tok_s[m] * HD + n], val);
            }
        }
    }
}

extern "C" void kernel_launch(void* const* d_in, const int* in_sizes, int n_in,
                              void* d_out, int out_size, void* d_ws, size_t ws_size,
                              hipStream_t stream)
{
    const float* x  = (const float*)d_in[0];
    const float* gW = (const float*)d_in[1];
    const float* gb = (const float*)d_in[2];
    const float* W1 = (const float*)d_in[3];
    const float* b1 = (const float*)d_in[4];
    const float* W2 = (const float*)d_in[5];
    const float* b2 = (const float*)d_in[6];
    float* out = (float*)d_out;

    // workspace layout
    int*   seg_count = (int*)d_ws;                                   // 8 ints @0
    float* probs_sum = (float*)((char*)d_ws + 32);                   // 8 floats
    int*   seg_token = (int*)((char*)d_ws + 256);                    // [NE][TOK]
    float* seg_w     = (float*)((char*)d_ws + 256 + (size_t)NE * TOK * 4);
    unsigned short* xb  = (unsigned short*)((char*)d_ws + (1u << 20));    // 8 MB
    unsigned short* W1t = (unsigned short*)((char*)d_ws + (16u << 20));   // 16 MB
    unsigned short* W2t = (unsigned short*)((char*)d_ws + (32u << 20));   // 16 MB

    hipMemsetAsync(d_ws, 0, 64, stream);
    hipMemsetAsync(d_out, 0, (size_t)TOK * HD * sizeof(float), stream);

    gate_kernel<<<TOK / 256, 256, 0, stream>>>(x, gW, gb, seg_count, probs_sum,
                                               seg_token, seg_w, xb);
    finalize_kernel<<<1, 64, 0, stream>>>(seg_count, probs_sum, out + (size_t)TOK * HD);

    // W1 [E][HD][DFF] -> W1t [E][DFF][HD]
    transpose_bf16_kernel<<<dim3(DFF / 64, HD / 64, NE), 256, 0, stream>>>(W1, W1t, HD, DFF);
    // W2 [E][DFF][HD] -> W2t [E][HD][DFF]
    transpose_bf16_kernel<<<dim3(HD / 64, DFF / 64, NE), 256, 0, stream>>>(W2, W2t, DFF, HD);

    ffn_mfma_kernel<<<(TOK / BMT) * ZN * NE, 256, 0, stream>>>(
        xb, W1t, b1, W2t, b2, seg_count, seg_token, seg_w, out);
}

// Round 6
// 439.686 us; speedup vs baseline: 2.8954x; 2.8954x over previous
//
#include <hip/hip_runtime.h>
#include <math.h>

#define TOK 8192   // B*S tokens
#define HD  512    // hidden
#define NE  8      // experts
#define DFF 2048   // ffn dim

// ---------- bf16 helpers ----------
typedef __attribute__((ext_vector_type(8))) short bf16x8;
typedef __attribute__((ext_vector_type(4))) float floatx4;

__device__ inline unsigned short f2bf(float f) {
    union { float f; unsigned u; } v; v.f = f;
    unsigned r = v.u + 0x7FFFu + ((v.u >> 16) & 1u);   // round-nearest-even
    return (unsigned short)(r >> 16);
}

__device__ inline float gelu_exact(float v) {
    return 0.5f * v * (1.f + erff(v * 0.70710678118654752f));
}

// ---------------- gating (fp32, exact) + fused x->bf16 conversion ----------------
__global__ __launch_bounds__(256) void gate_kernel(
    const float* __restrict__ x, const float* __restrict__ gW, const float* __restrict__ gb,
    int* __restrict__ seg_count, float* __restrict__ probs_sum,
    int* __restrict__ seg_token, float* __restrict__ seg_w,
    unsigned short* __restrict__ xb)
{
    __shared__ float sW[HD * NE];
    __shared__ float psum[NE];
    __shared__ int   lcount[NE];
    __shared__ int   lbase[NE];

    int tid = threadIdx.x;
    for (int i = tid; i < HD * NE; i += 256) sW[i] = gW[i];
    if (tid < NE) { psum[tid] = 0.f; lcount[tid] = 0; }
    __syncthreads();

    int t = blockIdx.x * 256 + tid;
    float logit[NE];
    #pragma unroll
    for (int e = 0; e < NE; e++) logit[e] = gb[e];

    const float4* xr4 = reinterpret_cast<const float4*>(x + (size_t)t * HD);
    ushort4* xbw = reinterpret_cast<ushort4*>(xb + (size_t)t * HD);
    for (int j4 = 0; j4 < HD / 4; j4++) {
        float4 xv = xr4[j4];
        int j = j4 * 4;
        ushort4 o; o.x = f2bf(xv.x); o.y = f2bf(xv.y); o.z = f2bf(xv.z); o.w = f2bf(xv.w);
        xbw[j4] = o;
        #pragma unroll
        for (int e = 0; e < NE; e++) {
            logit[e] += xv.x * sW[(j + 0) * NE + e] + xv.y * sW[(j + 1) * NE + e]
                      + xv.z * sW[(j + 2) * NE + e] + xv.w * sW[(j + 3) * NE + e];
        }
    }

    float mx = logit[0];
    #pragma unroll
    for (int e = 1; e < NE; e++) mx = fmaxf(mx, logit[e]);
    float pe[NE]; float s = 0.f;
    #pragma unroll
    for (int e = 0; e < NE; e++) { pe[e] = expf(logit[e] - mx); s += pe[e]; }
    float inv = 1.f / s;
    int l = tid & 63;
    #pragma unroll
    for (int e = 0; e < NE; e++) {          // wave-shuffle reduce, 1 LDS atomic per wave per e
        float v = pe[e] * inv;
        for (int off = 32; off; off >>= 1) v += __shfl_down(v, off);
        if (l == 0) atomicAdd(&psum[e], v);
    }

    // top-2, lowest-index tie break (matches jax.lax.top_k)
    int i0 = 0; float v0 = logit[0];
    #pragma unroll
    for (int e = 1; e < NE; e++) if (logit[e] > v0) { v0 = logit[e]; i0 = e; }
    int i1 = -1; float v1 = -3.4e38f;
    #pragma unroll
    for (int e = 0; e < NE; e++) if (e != i0 && logit[e] > v1) { v1 = logit[e]; i1 = e; }
    float e1 = expf(v1 - v0);
    float w0 = 1.f / (1.f + e1);
    float w1 = e1 / (1.f + e1);

    int r0 = atomicAdd(&lcount[i0], 1);
    int r1 = atomicAdd(&lcount[i1], 1);
    __syncthreads();
    if (tid < NE) lbase[tid] = atomicAdd(&seg_count[tid], lcount[tid]);
    __syncthreads();
    int p0 = lbase[i0] + r0;
    seg_token[i0 * TOK + p0] = t; seg_w[i0 * TOK + p0] = w0;
    int p1 = lbase[i1] + r1;
    seg_token[i1 * TOK + p1] = t; seg_w[i1 * TOK + p1] = w1;

    __syncthreads();
    if (tid < NE) atomicAdd(&probs_sum[tid], psum[tid]);
}

// ---------------- l_aux + counts ----------------
__global__ void finalize_kernel(const int* __restrict__ seg_count,
                                const float* __restrict__ probs_sum,
                                float* __restrict__ out_tail)
{
    int tid = threadIdx.x;
    __shared__ float p2[NE];
    if (tid < NE) {
        float p = probs_sum[tid] * (1.f / (float)TOK);
        p2[tid] = p * p;
        out_tail[1 + tid] = (float)seg_count[tid];
    }
    __syncthreads();
    if (tid == 0) {
        float ssum = 0.f;
        #pragma unroll
        for (int e = 0; e < NE; e++) ssum += p2[e];
        out_tail[0] = ssum * (float)NE;
    }
}

// ---------------- weight transpose: [E][R][C] fp32 -> [E][C][R] bf16 ----------------
__global__ __launch_bounds__(256) void transpose_bf16_kernel(const float* __restrict__ in,
                                                             unsigned short* __restrict__ out,
                                                             int R, int C)
{
    __shared__ float tile[64][65];
    int e = blockIdx.z;
    const float* src = in + (size_t)e * R * C;
    unsigned short* dst = out + (size_t)e * R * C;
    int c0 = blockIdx.x * 64, r0 = blockIdx.y * 64;
    int lc = threadIdx.x & 63, lrw = threadIdx.x >> 6;   // 4 row-groups
    #pragma unroll
    for (int rr = lrw; rr < 64; rr += 4)
        tile[rr][lc] = src[(size_t)(r0 + rr) * C + c0 + lc];
    __syncthreads();
    #pragma unroll
    for (int cc = lrw; cc < 64; cc += 4)
        dst[(size_t)(c0 + cc) * R + r0 + lc] = f2bf(tile[lc][cc]);
}

// ---------------- prefix + gather: build 128-padded per-expert row segments ----------------
#define RPAD 128
__global__ void prefix_gather_kernel(const int* __restrict__ seg_count,
                                     const int* __restrict__ seg_token,
                                     const float* __restrict__ seg_w,
                                     int* __restrict__ off_g,
                                     int* __restrict__ rtok, float* __restrict__ rwgt)
{
    __shared__ int off_s[NE + 1];
    if (threadIdx.x == 0) {
        int acc = 0;
        #pragma unroll
        for (int e = 0; e < NE; e++) {
            off_s[e] = acc; off_g[e] = acc;
            acc += ((seg_count[e] + RPAD - 1) / RPAD) * RPAD;
        }
        off_s[NE] = acc; off_g[NE] = acc;
    }
    __syncthreads();
    int total = off_s[NE];
    for (int i = threadIdx.x; i < total; i += 256) {
        int e = 0;
        #pragma unroll
        for (int ee = 0; ee < NE; ee++) if (i >= off_s[ee + 1]) e = ee + 1;
        int li = i - off_s[e];
        int cnt = seg_count[e];
        if (li < cnt) { rtok[i] = seg_token[e * TOK + li]; rwgt[i] = seg_w[e * TOK + li]; }
        else          { rtok[i] = seg_token[e * TOK];      rwgt[i] = 0.f; }   // pad: dup row0, weight 0
    }
}

// ---------------- split GEMM path ----------------
// 128x128 tiles, BK=64, 4 waves each computing 64x64 (4x4 MFMA frags).
#define TM  128
#define TN  128
#define BK  64
#define LDT 72    // padded LDS leading dim (ushorts): 144 B rows, bank-floor reads

// GEMM1: hbuf[row, n] = gelu( xb[rtok[row], :] @ W1t[e][n, :] + b1[e][n] )
__global__ __launch_bounds__(256) void gemm1_kernel(
    const unsigned short* __restrict__ xb,
    const unsigned short* __restrict__ W1t,   // [E][DFF][HD] n-major
    const float* __restrict__ b1,
    const int* __restrict__ seg_count, const int* __restrict__ off_g,
    const int* __restrict__ rtok,
    unsigned short* __restrict__ hbuf)        // [rows][DFF]
{
    int bid = blockIdx.x;
    int e   = bid & 7;                         // low bits -> XCD affinity
    int r2  = bid >> 3;
    int nb  = r2 & (DFF / TN - 1);             // 0..15
    int mb  = r2 >> 4;                         // 0..63
    int cnt = seg_count[e];
    if (mb * TM >= cnt) return;
    int hb = off_g[e] + mb * TM;

    __shared__ unsigned short smem[2 * TM * LDT];   // As | Bs; reused as epilogue scratch
    unsigned short* As = smem;
    unsigned short* Bs = smem + TM * LDT;
    __shared__ int tok_s[TM];

    int tid = threadIdx.x;
    if (tid < TM) tok_s[tid] = rtok[hb + tid];
    __syncthreads();

    int w = tid >> 6, l = tid & 63;
    int lr = l & 15, lk = (l >> 4) * 8, crow = (l >> 4) * 4;
    int wm = (w & 1) * 64, wn = (w >> 1) * 64;

    const unsigned short* w1e = W1t + (size_t)e * DFF * HD + (size_t)(nb * TN) * HD;

    floatx4 acc[4][4];
    #pragma unroll
    for (int i = 0; i < 4; i++)
        #pragma unroll
        for (int j = 0; j < 4; j++) acc[i][j] = (floatx4){0.f, 0.f, 0.f, 0.f};

    int sr = tid >> 1, sh = (tid & 1) * 32;    // staging: 2 threads/row, 64 B each
    for (int k0 = 0; k0 < HD; k0 += BK) {
        const uint4* sa = (const uint4*)(xb + (size_t)tok_s[sr] * HD + k0 + sh);
        uint4* da = (uint4*)&As[sr * LDT + sh];
        da[0] = sa[0]; da[1] = sa[1]; da[2] = sa[2]; da[3] = sa[3];
        const uint4* sb = (const uint4*)(w1e + (size_t)sr * HD + k0 + sh);
        uint4* db = (uint4*)&Bs[sr * LDT + sh];
        db[0] = sb[0]; db[1] = sb[1]; db[2] = sb[2]; db[3] = sb[3];
        __syncthreads();
        #pragma unroll
        for (int ks = 0; ks < BK; ks += 32) {
            bf16x8 a[4], b[4];
            #pragma unroll
            for (int i = 0; i < 4; i++) a[i] = *(const bf16x8*)&As[(wm + 16 * i + lr) * LDT + ks + lk];
            #pragma unroll
            for (int j = 0; j < 4; j++) b[j] = *(const bf16x8*)&Bs[(wn + 16 * j + lr) * LDT + ks + lk];
            #pragma unroll
            for (int i = 0; i < 4; i++)
                #pragma unroll
                for (int j = 0; j < 4; j++)
                    acc[i][j] = __builtin_amdgcn_mfma_f32_16x16x32_bf16(a[i], b[j], acc[i][j], 0, 0, 0);
        }
        __syncthreads();
    }

    // epilogue: +b1, gelu, bf16 -> per-wave LDS scratch -> coalesced 16B stores
    unsigned short* scr = smem + w * 64 * LDT;
    #pragma unroll
    for (int j = 0; j < 4; j++) {
        float b1v = b1[e * DFF + nb * TN + wn + 16 * j + lr];
        #pragma unroll
        for (int i = 0; i < 4; i++)
            #pragma unroll
            for (int rr = 0; rr < 4; rr++)
                scr[(16 * i + crow + rr) * LDT + 16 * j + lr] = f2bf(gelu_exact(acc[i][j][rr] + b1v));
    }
    int lh = l >> 3, ll = l & 7;
    #pragma unroll
    for (int k = 0; k < 8; k++) {
        uint4 v = *(const uint4*)&scr[(8 * k + lh) * LDT + ll * 8];
        int grow = hb + wm + 8 * k + lh;
        *(uint4*)&hbuf[(size_t)grow * DFF + nb * TN + wn + ll * 8] = v;
    }
}

// GEMM2: out[rtok[row], n] += rwgt[row] * ( hbuf[row, :] @ W2t[e][n, :] + b2[e][n] )
__global__ __launch_bounds__(256) void gemm2_kernel(
    const unsigned short* __restrict__ hbuf,
    const unsigned short* __restrict__ W2t,   // [E][HD][DFF] n-major
    const float* __restrict__ b2,
    const int* __restrict__ seg_count, const int* __restrict__ off_g,
    const int* __restrict__ rtok, const float* __restrict__ rwgt,
    float* __restrict__ out)
{
    int bid = blockIdx.x;
    int e   = bid & 7;
    int r2  = bid >> 3;
    int nb  = r2 & (HD / TN - 1);              // 0..3
    int mb  = r2 >> 2;                         // 0..63
    int cnt = seg_count[e];
    if (mb * TM >= cnt) return;
    int hb = off_g[e] + mb * TM;

    __shared__ unsigned short As[TM * LDT];
    __shared__ unsigned short Bs[TM * LDT];
    __shared__ int   tok_s[TM];
    __shared__ float wgt_s[TM];

    int tid = threadIdx.x;
    if (tid < TM) { tok_s[tid] = rtok[hb + tid]; wgt_s[tid] = rwgt[hb + tid]; }
    __syncthreads();

    int w = tid >> 6, l = tid & 63;
    int lr = l & 15, lk = (l >> 4) * 8, crow = (l >> 4) * 4;
    int wm = (w & 1) * 64, wn = (w >> 1) * 64;

    const unsigned short* w2e = W2t + (size_t)e * HD * DFF + (size_t)(nb * TN) * DFF;

    floatx4 acc[4][4];
    #pragma unroll
    for (int i = 0; i < 4; i++)
        #pragma unroll
        for (int j = 0; j < 4; j++) acc[i][j] = (floatx4){0.f, 0.f, 0.f, 0.f};

    int sr = tid >> 1, sh = (tid & 1) * 32;
    for (int k0 = 0; k0 < DFF; k0 += BK) {
        const uint4* sa = (const uint4*)(hbuf + (size_t)(hb + sr) * DFF + k0 + sh);
        uint4* da = (uint4*)&As[sr * LDT + sh];
        da[0] = sa[0]; da[1] = sa[1]; da[2] = sa[2]; da[3] = sa[3];
        const uint4* sb = (const uint4*)(w2e + (size_t)sr * DFF + k0 + sh);
        uint4* db = (uint4*)&Bs[sr * LDT + sh];
        db[0] = sb[0]; db[1] = sb[1]; db[2] = sb[2]; db[3] = sb[3];
        __syncthreads();
        #pragma unroll
        for (int ks = 0; ks < BK; ks += 32) {
            bf16x8 a[4], b[4];
            #pragma unroll
            for (int i = 0; i < 4; i++) a[i] = *(const bf16x8*)&As[(wm + 16 * i + lr) * LDT + ks + lk];
            #pragma unroll
            for (int j = 0; j < 4; j++) b[j] = *(const bf16x8*)&Bs[(wn + 16 * j + lr) * LDT + ks + lk];
            #pragma unroll
            for (int i = 0; i < 4; i++)
                #pragma unroll
                for (int j = 0; j < 4; j++)
                    acc[i][j] = __builtin_amdgcn_mfma_f32_16x16x32_bf16(a[i], b[j], acc[i][j], 0, 0, 0);
        }
        __syncthreads();
    }

    // epilogue: +b2, x gate weight, atomicAdd (2 adds/element total across experts)
    #pragma unroll
    for (int j = 0; j < 4; j++) {
        int n = nb * TN + wn + 16 * j + lr;
        float b2v = b2[e * HD + n];
        #pragma unroll
        for (int i = 0; i < 4; i++)
            #pragma unroll
            for (int rr = 0; rr < 4; rr++) {
                int m = wm + 16 * i + crow + rr;
                atomicAdd(&out[(size_t)tok_s[m] * HD + n], (acc[i][j][rr] + b2v) * wgt_s[m]);
            }
    }
}

// ---------------- fused fallback (ws too small): R2-style, ZN=1, swizzled ----------------
#define BMT 64
#define FK  64
#define XS_LD 520
#define HS_LD 72

__global__ __launch_bounds__(256, 2) void ffn_fused_fallback(
    const unsigned short* __restrict__ xb,
    const unsigned short* __restrict__ W1t, const float* __restrict__ b1,
    const unsigned short* __restrict__ W2t, const float* __restrict__ b2,
    const int* __restrict__ seg_count, const int* __restrict__ seg_token,
    const float* __restrict__ seg_w, float* __restrict__ out)
{
    int bid = blockIdx.x;
    int e = bid & 7;
    int g = bid >> 3;
    int cnt = seg_count[e];
    int n0 = g * BMT;
    if (n0 >= cnt) return;
    int rows = min(BMT, cnt - n0);

    __shared__ unsigned short xs[BMT * XS_LD];
    __shared__ unsigned short hs[BMT * HS_LD];
    __shared__ int   tok_s[BMT];
    __shared__ float wgt_s[BMT];

    int tid = threadIdx.x;
    if (tid < BMT) {
        int idx = (tid < rows) ? (n0 + tid) : n0;
        tok_s[tid] = seg_token[e * TOK + idx];
        wgt_s[tid] = (tid < rows) ? seg_w[e * TOK + idx] : 0.f;
    }
    __syncthreads();
    {
        int r = tid >> 2, q = tid & 3;
        const uint4* src = (const uint4*)(xb + (size_t)tok_s[r] * HD) + q * 16;
        uint4* dst = (uint4*)&xs[(size_t)r * XS_LD + q * 128];
        #pragma unroll
        for (int i = 0; i < 16; i++) dst[i] = src[i];
    }
    __syncthreads();

    int w = tid >> 6, l = tid & 63;
    int lr = l & 15, lk = (l >> 4) * 8, crow = (l >> 4) * 4;

    const unsigned short* w1e = W1t + (size_t)e * DFF * HD;
    const unsigned short* w2e = W2t + (size_t)e * HD * DFF;

    floatx4 acc2[4][8];
    #pragma unroll
    for (int i = 0; i < 4; i++)
        #pragma unroll
        for (int j = 0; j < 8; j++) acc2[i][j] = (floatx4){0.f, 0.f, 0.f, 0.f};

    for (int fc = 0; fc < DFF; fc += FK) {
        floatx4 acc1[4];
        #pragma unroll
        for (int t = 0; t < 4; t++) acc1[t] = (floatx4){0.f, 0.f, 0.f, 0.f};
        const unsigned short* w1c = w1e + (size_t)fc * HD;
        for (int ks = 0; ks < HD; ks += 32) {
            bf16x8 a = *(const bf16x8*)&xs[(16 * w + lr) * XS_LD + ks + lk];
            #pragma unroll
            for (int t = 0; t < 4; t++) {
                bf16x8 b = *(const bf16x8*)(w1c + (size_t)(16 * t + lr) * HD + ks + lk);
                acc1[t] = __builtin_amdgcn_mfma_f32_16x16x32_bf16(a, b, acc1[t], 0, 0, 0);
            }
        }
        __syncthreads();
        #pragma unroll
        for (int t = 0; t < 4; t++) {
            float b1v = b1[e * DFF + fc + 16 * t + lr];
            #pragma unroll
            for (int r = 0; r < 4; r++)
                hs[(16 * w + crow + r) * HS_LD + 16 * t + lr] = f2bf(gelu_exact(acc1[t][r] + b1v));
        }
        __syncthreads();
        #pragma unroll
        for (int ks = 0; ks < FK; ks += 32) {
            bf16x8 af[4];
            #pragma unroll
            for (int i = 0; i < 4; i++) af[i] = *(const bf16x8*)&hs[(16 * i + lr) * HS_LD + ks + lk];
            #pragma unroll 4
            for (int j = 0; j < 8; j++) {
                bf16x8 b = *(const bf16x8*)(w2e + (size_t)(128 * w + 16 * j + lr) * DFF + fc + ks + lk);
                #pragma unroll
                for (int i = 0; i < 4; i++)
                    acc2[i][j] = __builtin_amdgcn_mfma_f32_16x16x32_bf16(af[i], b, acc2[i][j], 0, 0, 0);
            }
        }
    }
    #pragma unroll
    for (int j = 0; j < 8; j++) {
        int n = 128 * w + 16 * j + lr;
        float b2v = b2[e * HD + n];
        #pragma unroll
        for (int i = 0; i < 4; i++)
            #pragma unroll
            for (int r = 0; r < 4; r++) {
                int m = 16 * i + crow + r;
                atomicAdd(&out[(size_t)tok_s[m] * HD + n], (acc2[i][j][r] + b2v) * wgt_s[m]);
            }
    }
}

extern "C" void kernel_launch(void* const* d_in, const int* in_sizes, int n_in,
                              void* d_out, int out_size, void* d_ws, size_t ws_size,
                              hipStream_t stream)
{
    const float* x  = (const float*)d_in[0];
    const float* gW = (const float*)d_in[1];
    const float* gb = (const float*)d_in[2];
    const float* W1 = (const float*)d_in[3];
    const float* b1 = (const float*)d_in[4];
    const float* W2 = (const float*)d_in[5];
    const float* b2 = (const float*)d_in[6];
    float* out = (float*)d_out;

    // workspace layout (bytes)
    char* ws = (char*)d_ws;
    int*   seg_count = (int*)ws;                          // 32 B
    float* probs_sum = (float*)(ws + 32);                 // 32 B
    int*   off_g     = (int*)(ws + 128);                  // 36 B
    int*   rtok      = (int*)(ws + 1024);                 // 17408*4
    float* rwgt      = (float*)(ws + 1024 + 17408 * 4);
    int*   seg_token = (int*)(ws + 262144);               // NE*TOK*4
    float* seg_w     = (float*)(ws + 262144 + (size_t)NE * TOK * 4);
    unsigned short* xb   = (unsigned short*)(ws + (1u  << 20));  //  8 MiB
    unsigned short* W1t  = (unsigned short*)(ws + (16u << 20));  // 16 MiB
    unsigned short* W2t  = (unsigned short*)(ws + (32u << 20));  // 16 MiB
    unsigned short* hbuf = (unsigned short*)(ws + (48u << 20));  // 71.3 MB

    const size_t WS_SPLIT = (size_t)(48u << 20) + (size_t)17408 * DFF * 2;  // ~122 MB

    hipMemsetAsync(d_ws, 0, 64, stream);
    hipMemsetAsync(d_out, 0, (size_t)TOK * HD * sizeof(float), stream);

    gate_kernel<<<TOK / 256, 256, 0, stream>>>(x, gW, gb, seg_count, probs_sum,
                                               seg_token, seg_w, xb);
    finalize_kernel<<<1, 64, 0, stream>>>(seg_count, probs_sum, out + (size_t)TOK * HD);

    // W1 [E][HD][DFF] -> W1t [E][DFF][HD];  W2 [E][DFF][HD] -> W2t [E][HD][DFF]
    transpose_bf16_kernel<<<dim3(DFF / 64, HD / 64, NE), 256, 0, stream>>>(W1, W1t, HD, DFF);
    transpose_bf16_kernel<<<dim3(HD / 64, DFF / 64, NE), 256, 0, stream>>>(W2, W2t, DFF, HD);

    if (ws_size >= WS_SPLIT) {
        prefix_gather_kernel<<<1, 256, 0, stream>>>(seg_count, seg_token, seg_w,
                                                    off_g, rtok, rwgt);
        // GEMM1: NE * 64 mslots * 16 nblocks = 8192 slots (~2176 working)
        gemm1_kernel<<<NE * 64 * (DFF / TN), 256, 0, stream>>>(
            xb, W1t, b1, seg_count, off_g, rtok, hbuf);
        // GEMM2: NE * 64 mslots * 4 nblocks = 2048 slots (~544 working)
        gemm2_kernel<<<NE * 64 * (HD / TN), 256, 0, stream>>>(
            hbuf, W2t, b2, seg_count, off_g, rtok, rwgt, out);
    } else {
        ffn_fused_fallback<<<(TOK / BMT) * NE, 256, 0, stream>>>(
            xb, W1t, b1, W2t, b2, seg_count, seg_token, seg_w, out);
    }
}